// Round 1
// baseline (13284.384 us; speedup 1.0000x reference)
//
#include <hip/hip_runtime.h>
#include <math.h>

// DirModelToFace on MI355X — round 1: correct fp32 baseline.
// Structure per dir block: memset msg -> spmm(atomics) -> stats -> fold(BN into W) -> GEMM.
// Per avg block: masked avgpool -> stats -> fold -> GEMM (avg half folded as broadcast B-source).
// GEMM: 64x128 tile, 128 threads, 8x8 per-thread register tile, LDS-staged X(transposed)+W.

#define EPS 1e-5f

__device__ __forceinline__ float eluf(float x) { return x > 0.f ? x : expm1f(x); }
__device__ __forceinline__ float4 elu4(float4 v) {
    v.x = eluf(v.x); v.y = eluf(v.y); v.z = eluf(v.z); v.w = eluf(v.w); return v;
}

// v = inputs @ W1 + b1   (inputs [BN,3], W1 [3,128])
__global__ void conv1_kernel(const float* __restrict__ in, const float* __restrict__ W1,
                             const float* __restrict__ b1, float* __restrict__ v) {
    int idx = blockIdx.x * 256 + threadIdx.x;
    int r = idx >> 7, c = idx & 127;
    float x0 = in[r * 3 + 0], x1 = in[r * 3 + 1], x2 = in[r * 3 + 2];
    v[(size_t)r * 128 + c] = b1[c] + x0 * W1[c] + x1 * W1[128 + c] + x2 * W1[256 + c];
}

// COO spmm with atomics: y[b, rows[e], 0:32] += vals[e] * x[b, cols[e], 0:32]
__global__ void spmm_kernel(const int* __restrict__ rows, const int* __restrict__ cols,
                            const float* __restrict__ vals, const float* __restrict__ x,
                            float* __restrict__ y, int K4, int R4) {
    long idx = (long)blockIdx.x * 256 + threadIdx.x;
    int e = (int)(idx >> 7);
    int l = (int)(idx & 127);
    int b = l >> 5, c = l & 31;
    int ro = rows[e], co = cols[e];
    float va = vals[e];
    float xv = x[((size_t)b * K4 + co) * 32 + c];
    atomicAdd(&y[((size_t)b * R4 + ro) * 32 + c], va * xv);
}

// per-channel sums/sumsq over rows of X = [elu(A) | B-half]; S[0:256]=sum, S[256:512]=sumsq
__global__ void stats_kernel(const float* __restrict__ A, const float* __restrict__ Bs,
                             float* __restrict__ S, int R, int rpb, int rowsPerBatch,
                             int modeB, int eluB) {
    int t = threadIdx.x;
    int r0 = blockIdx.x * rpb;
    int r1 = min(r0 + rpb, R);
    float s1 = 0.f, s2 = 0.f;
    if (t < 128) {
        for (int r = r0; r < r1; ++r) {
            float v = eluf(A[(size_t)r * 128 + t]);
            s1 += v; s2 += v * v;
        }
    } else {
        int c = t - 128;
        if (modeB == 0) {
            for (int r = r0; r < r1; ++r) {
                float v = Bs[(size_t)r * 128 + c];
                if (eluB) v = eluf(v);
                s1 += v; s2 += v * v;
            }
        } else {
            for (int r = r0; r < r1; ++r) {
                float v = Bs[(r / rowsPerBatch) * 128 + c];
                s1 += v; s2 += v * v;
            }
        }
    }
    atomicAdd(&S[t], s1);
    atomicAdd(&S[256 + t], s2);
}

// Fold BN into weights: Wp[k,o] = s_k*W[k,o]; bp[o] = b[o] + sum_k (beta_k - mean_k*s_k)*W[k,o]
__global__ void fold_kernel(const float* __restrict__ S, const float* __restrict__ gamma,
                            const float* __restrict__ beta, const float* __restrict__ W,
                            const float* __restrict__ bvec, float* __restrict__ Wp,
                            float* __restrict__ bp, float invR) {
    __shared__ float red[256];
    int o = blockIdx.x, k = threadIdx.x;
    float mean = S[k] * invR;
    float var = S[256 + k] * invR - mean * mean;
    float s = gamma[k] / sqrtf(var + EPS);
    float w = W[(size_t)k * 128 + o];
    Wp[(size_t)k * 128 + o] = s * w;
    red[k] = (beta[k] - mean * s) * w;
    __syncthreads();
    for (int st = 128; st > 0; st >>= 1) {
        if (k < st) red[k] += red[k + st];
        __syncthreads();
    }
    if (k == 0) bp[o] = bvec[o] + red[0];
}

// GEMM: out[r, 0:128] = X[r, 0:256] @ Wp + bp (+ resid). X half A = elu(A[r]), half B per mode.
__global__ __launch_bounds__(128) void gemm256(
    const float* __restrict__ A, const float* __restrict__ Bs,
    const float* __restrict__ Wp, const float* __restrict__ bp,
    const float* __restrict__ resid, float* __restrict__ out,
    int rowsPerBatch, int modeB, int eluB) {
    __shared__ float Xs[32][68];   // [kk][row] transposed, padded
    __shared__ float Ws[32][132];  // [kk][col] padded
    const int t = threadIdx.x;
    const int tcol = t & 15, trow = t >> 4;
    const int rowBase = blockIdx.x * 64;
    float acc[8][8];
#pragma unroll
    for (int i = 0; i < 8; ++i)
#pragma unroll
        for (int j = 0; j < 8; ++j) acc[i][j] = 0.f;

    for (int kb = 0; kb < 8; ++kb) {
        __syncthreads();
        // stage W slab 32x128
#pragma unroll
        for (int j = 0; j < 8; ++j) {
            int idx = t + 128 * j;
            int kr = idx >> 5, cq = (idx & 31) << 2;
            float4 w = *(const float4*)&Wp[(size_t)(kb * 32 + kr) * 128 + cq];
            *(float4*)&Ws[kr][cq] = w;
        }
        // stage X slab 64 rows x 32 k
#pragma unroll
        for (int j = 0; j < 4; ++j) {
            int idx = t + 128 * j;
            int row = idx >> 3, q = idx & 7;
            int gr = rowBase + row;
            int lc = q * 4;
            float4 v;
            if (kb < 4) {
                v = elu4(*(const float4*)&A[(size_t)gr * 128 + kb * 32 + lc]);
            } else if (modeB == 0) {
                v = *(const float4*)&Bs[(size_t)gr * 128 + (kb - 4) * 32 + lc];
                if (eluB) v = elu4(v);
            } else {
                int b = gr / rowsPerBatch;
                v = *(const float4*)&Bs[b * 128 + (kb - 4) * 32 + lc];
            }
            Xs[lc + 0][row] = v.x;
            Xs[lc + 1][row] = v.y;
            Xs[lc + 2][row] = v.z;
            Xs[lc + 3][row] = v.w;
        }
        __syncthreads();
#pragma unroll
        for (int kk = 0; kk < 32; ++kk) {
            float4 x0 = *(const float4*)&Xs[kk][trow * 8];
            float4 x1 = *(const float4*)&Xs[kk][trow * 8 + 4];
            float4 w0 = *(const float4*)&Ws[kk][tcol * 8];
            float4 w1 = *(const float4*)&Ws[kk][tcol * 8 + 4];
            float xv[8] = {x0.x, x0.y, x0.z, x0.w, x1.x, x1.y, x1.z, x1.w};
            float wv[8] = {w0.x, w0.y, w0.z, w0.w, w1.x, w1.y, w1.z, w1.w};
#pragma unroll
            for (int i = 0; i < 8; ++i)
#pragma unroll
                for (int j = 0; j < 8; ++j) acc[i][j] += xv[i] * wv[j];
        }
    }
    const int c0 = tcol * 8;
    float4 b0 = *(const float4*)&bp[c0];
    float4 b1 = *(const float4*)&bp[c0 + 4];
#pragma unroll
    for (int i = 0; i < 8; ++i) {
        size_t ro = (size_t)(rowBase + trow * 8 + i) * 128 + c0;
        float4 o0 = make_float4(acc[i][0] + b0.x, acc[i][1] + b0.y, acc[i][2] + b0.z, acc[i][3] + b0.w);
        float4 o1 = make_float4(acc[i][4] + b1.x, acc[i][5] + b1.y, acc[i][6] + b1.z, acc[i][7] + b1.w);
        if (resid) {
            float4 r0 = *(const float4*)&resid[ro];
            float4 r1 = *(const float4*)&resid[ro + 4];
            o0.x += r0.x; o0.y += r0.y; o0.z += r0.z; o0.w += r0.w;
            o1.x += r1.x; o1.y += r1.y; o1.z += r1.z; o1.w += r1.w;
        }
        *(float4*)&out[ro] = o0;
        *(float4*)&out[ro + 4] = o1;
    }
}

// masked mean of elu(X) over rows per batch: partial sums via atomics
__global__ void avgpool_kernel(const float* __restrict__ X, const float* __restrict__ mask,
                               float* __restrict__ avgacc, float* __restrict__ masksum,
                               int N, int rpb) {
    int b = blockIdx.y, t = threadIdx.x;
    int n0 = blockIdx.x * rpb;
    int n1 = min(n0 + rpb, N);
    float acc = 0.f, mac = 0.f;
    for (int n = n0; n < n1; ++n) {
        float m = mask[(size_t)b * N + n];
        float v = eluf(X[((size_t)b * N + n) * 128 + t]);
        acc += m * v;
        mac += m;
    }
    atomicAdd(&avgacc[b * 128 + t], acc);
    if (t == 0) atomicAdd(&masksum[b], mac);
}

// avg[b,c] = acc/masksum; also fill broadcast-half BN sums: S[128+c], S[384+c]
__global__ void finalize_avg(const float* __restrict__ avgacc, const float* __restrict__ masksum,
                             float* __restrict__ avg, float* __restrict__ S, float fN) {
    int c = threadIdx.x;
    float s1 = 0.f, s2 = 0.f;
    for (int b = 0; b < 4; ++b) {
        float a = avgacc[b * 128 + c] / masksum[b];
        avg[b * 128 + c] = a;
        s1 += a; s2 += a * a;
    }
    S[128 + c] = s1 * fN;
    S[256 + 128 + c] = s2 * fN;
}

// final conv fold: W2p[c] = s_c*W2[c]; W2p[128] = b2 + sum_c (be2_c - mean_c*s_c)*W2[c]
__global__ void fold_final(const float* __restrict__ S, const float* __restrict__ g2,
                           const float* __restrict__ be2, const float* __restrict__ W2,
                           const float* __restrict__ b2, float* __restrict__ W2p, float invR) {
    __shared__ float red[128];
    int c = threadIdx.x;
    float mean = S[c] * invR;
    float var = S[256 + c] * invR - mean * mean;
    float s = g2[c] / sqrtf(var + EPS);
    float w = W2[c];
    W2p[c] = s * w;
    red[c] = (be2[c] - mean * s) * w;
    __syncthreads();
    for (int st = 64; st > 0; st >>= 1) {
        if (c < st) red[c] += red[c + st];
        __syncthreads();
    }
    if (c == 0) W2p[128] = b2[0] + red[0];
}

// out[row] = elu(f[row,:]) . W2p[0:128] + W2p[128]; one wave per row
__global__ void final_out_kernel(const float* __restrict__ f, const float* __restrict__ W2p,
                                 float* __restrict__ out) {
    int t = threadIdx.x;
    int w = t >> 6, lane = t & 63;
    int row = blockIdx.x * 4 + w;
    float a = eluf(f[(size_t)row * 128 + lane]) * W2p[lane] +
              eluf(f[(size_t)row * 128 + 64 + lane]) * W2p[64 + lane];
    for (int off = 32; off > 0; off >>= 1) a += __shfl_down(a, off);
    if (lane == 0) out[row] = a + W2p[128];
}

extern "C" void kernel_launch(void* const* d_in, const int* in_sizes, int n_in,
                              void* d_out, int out_size, void* d_ws, size_t ws_size,
                              hipStream_t stream) {
    const float* inputs = (const float*)d_in[0];
    const float* mask = (const float*)d_in[1];
    const int* Di_rows = (const int*)d_in[2];
    const int* Di_cols = (const int*)d_in[3];
    const float* Di_vals = (const float*)d_in[4];
    const int* DiA_rows = (const int*)d_in[5];
    const int* DiA_cols = (const int*)d_in[6];
    const float* DiA_vals = (const float*)d_in[7];
    const float* W1 = (const float*)d_in[8];
    const float* b1 = (const float*)d_in[9];
    const float* rn_gamma = (const float*)d_in[10];
    const float* rn_beta = (const float*)d_in[11];
    const float* rn_W = (const float*)d_in[12];
    const float* rn_b = (const float*)d_in[13];
    const float* g2 = (const float*)d_in[14];
    const float* be2 = (const float*)d_in[15];
    const float* W2 = (const float*)d_in[16];
    const float* b2 = (const float*)d_in[17];
    float* out = (float*)d_out;

    const int B = 4;
    const int BN = in_sizes[1];      // B*N = 48000
    const int N = BN / B;            // 12000
    const int BF = out_size;         // B*Fn = 96000
    const int Fn = BF / B;           // 24000
    const int nnz = in_sizes[2];     // 1,152,000

    // workspace layout (floats); ~148 MB total
    float* ws = (float*)d_ws;
    size_t off = 0;
    float* vA = ws + off;  off += (size_t)BN * 128;   // vertex features (in-place updated)
    float* xT = ws + off;  off += (size_t)BN * 128;   // avg-block intermediate
    float* fA = ws + off;  off += (size_t)BF * 128;   // face features (in-place updated)
    float* msg = ws + off; off += (size_t)BF * 128;   // spmm output (reused v/f sizes)
    float* S = ws + off;      off += 512;             // BN sums/sumsq
    float* avgacc = ws + off; off += 512;
    float* masksum = ws + off; off += 4;
    float* avg = ws + off;    off += 512;
    float* Wp = ws + off;  off += 256 * 128;          // folded weights
    float* bp = ws + off;  off += 128;                // folded bias
    float* W2p = ws + off; off += 132;                // final folded weights + bias

    const int spmmBlocks = (int)(((long)nnz * 128) / 256);

    hipMemsetAsync(fA, 0, (size_t)BF * 128 * 4, stream);
    conv1_kernel<<<BN * 128 / 256, 256, 0, stream>>>(inputs, W1, b1, vA);

    for (int i = 0; i < 16; ++i) {
        if ((i & 1) == 0) {
            // ---- dir block ----
            const float* g0 = rn_gamma + (size_t)(i * 2 + 0) * 256;
            const float* be0 = rn_beta + (size_t)(i * 2 + 0) * 256;
            const float* Wl0 = rn_W + (size_t)(i * 2 + 0) * 256 * 128;
            const float* bl0 = rn_b + (size_t)(i * 2 + 0) * 128;
            const float* g1 = rn_gamma + (size_t)(i * 2 + 1) * 256;
            const float* be1 = rn_beta + (size_t)(i * 2 + 1) * 256;
            const float* Wl1 = rn_W + (size_t)(i * 2 + 1) * 256 * 128;
            const float* bl1 = rn_b + (size_t)(i * 2 + 1) * 128;

            // msg_v = DiA @ f
            hipMemsetAsync(msg, 0, (size_t)BN * 128 * 4, stream);
            spmm_kernel<<<spmmBlocks, 256, 0, stream>>>(DiA_rows, DiA_cols, DiA_vals, fA, msg,
                                                        4 * Fn, 4 * N);
            hipMemsetAsync(S, 0, 512 * 4, stream);
            stats_kernel<<<BN / 64, 256, 0, stream>>>(vA, msg, S, BN, 64, N, 0, 1);
            fold_kernel<<<128, 256, 0, stream>>>(S, g0, be0, Wl0, bl0, Wp, bp, 1.f / BN);
            gemm256<<<BN / 64, 128, 0, stream>>>(vA, msg, Wp, bp, vA, vA, N, 0, 1);

            // msg_f = Di @ v_out
            hipMemsetAsync(msg, 0, (size_t)BF * 128 * 4, stream);
            spmm_kernel<<<spmmBlocks, 256, 0, stream>>>(Di_rows, Di_cols, Di_vals, vA, msg,
                                                        4 * N, 4 * Fn);
            hipMemsetAsync(S, 0, 512 * 4, stream);
            stats_kernel<<<BF / 64, 256, 0, stream>>>(fA, msg, S, BF, 64, Fn, 0, 1);
            fold_kernel<<<128, 256, 0, stream>>>(S, g1, be1, Wl1, bl1, Wp, bp, 1.f / BF);
            gemm256<<<BF / 64, 128, 0, stream>>>(fA, msg, Wp, bp, nullptr, fA, Fn, 0, 1);
        } else {
            // ---- avg block ----
            for (int j = 0; j < 2; ++j) {
                const float* g = rn_gamma + (size_t)(i * 2 + j) * 256;
                const float* be = rn_beta + (size_t)(i * 2 + j) * 256;
                const float* Wl = rn_W + (size_t)(i * 2 + j) * 256 * 128;
                const float* bl = rn_b + (size_t)(i * 2 + j) * 128;
                const float* src = (j == 0) ? vA : xT;
                float* dst = (j == 0) ? xT : vA;
                const float* resid = (j == 0) ? nullptr : vA;

                hipMemsetAsync(avgacc, 0, (512 + 4) * 4, stream);  // avgacc + masksum
                avgpool_kernel<<<dim3(N / 50, B), 128, 0, stream>>>(src, mask, avgacc, masksum,
                                                                    N, 50);
                hipMemsetAsync(S, 0, 512 * 4, stream);
                finalize_avg<<<1, 128, 0, stream>>>(avgacc, masksum, avg, S, (float)N);
                stats_kernel<<<BN / 64, 128, 0, stream>>>(src, nullptr, S, BN, 64, N, 0, 0);
                fold_kernel<<<128, 256, 0, stream>>>(S, g, be, Wl, bl, Wp, bp, 1.f / BN);
                gemm256<<<BN / 64, 128, 0, stream>>>(src, avg, Wp, bp, resid, dst, N, 1, 0);
            }
        }
    }

    // final conv2 on elu(f)
    hipMemsetAsync(S, 0, 512 * 4, stream);
    stats_kernel<<<BF / 64, 128, 0, stream>>>(fA, nullptr, S, BF, 64, Fn, 0, 0);
    fold_final<<<1, 128, 0, stream>>>(S, g2, be2, W2, b2, W2p, 1.f / BF);
    final_out_kernel<<<BF / 4, 256, 0, stream>>>(fA, W2p, out);
}

// Round 2
// 8227.008 us; speedup vs baseline: 1.6147x; 1.6147x over previous
//
#include <hip/hip_runtime.h>
#include <math.h>

// DirModelToFace on MI355X — round 2: CSR-based gather spmm (no atomics).
// Round 1 profile: spmm(atomics) = 477us x16 = 7.6ms of 13.3ms; WRITE_SIZE 576MB
// per spmm (12x output size) -> atomic scatter thrashes L2. Fix: on-device CSR
// build per launch (reused 8x per matrix), gather spmm with one wave per row.

#define EPS 1e-5f

__device__ __forceinline__ float eluf(float x) { return x > 0.f ? x : expm1f(x); }
__device__ __forceinline__ float4 elu4(float4 v) {
    v.x = eluf(v.x); v.y = eluf(v.y); v.z = eluf(v.z); v.w = eluf(v.w); return v;
}

// v = inputs @ W1 + b1   (inputs [BN,3], W1 [3,128])
__global__ void conv1_kernel(const float* __restrict__ in, const float* __restrict__ W1,
                             const float* __restrict__ b1, float* __restrict__ v) {
    int idx = blockIdx.x * 256 + threadIdx.x;
    int r = idx >> 7, c = idx & 127;
    float x0 = in[r * 3 + 0], x1 = in[r * 3 + 1], x2 = in[r * 3 + 2];
    v[(size_t)r * 128 + c] = b1[c] + x0 * W1[c] + x1 * W1[128 + c] + x2 * W1[256 + c];
}

// ---------------- CSR build (per launch; amortized over 8 spmm uses) ----------------

__global__ void hist_kernel(const int* __restrict__ rows, int* __restrict__ counts) {
    int e = blockIdx.x * 256 + threadIdx.x;
    atomicAdd(&counts[rows[e]], 1);
}

// single-block exclusive scan: rowptr[0..R-1] = exclusive prefix of counts; rowptr[R]=total
__global__ void scan_kernel(const int* __restrict__ counts, int* __restrict__ rowptr,
                            int R, int total) {
    __shared__ int sh[1024];
    int t = threadIdx.x;
    int carry = 0;
    for (int base = 0; base < R; base += 1024) {
        int i = base + t;
        int v = (i < R) ? counts[i] : 0;
        __syncthreads();
        sh[t] = v;
        __syncthreads();
        for (int st = 1; st < 1024; st <<= 1) {
            int tmp = (t >= st) ? sh[t - st] : 0;
            __syncthreads();
            if (t >= st) sh[t] += tmp;
            __syncthreads();
        }
        if (i < R) rowptr[i] = carry + sh[t] - v;
        carry += sh[1023];
    }
    if (t == 0) rowptr[R] = total;
}

__global__ void scatter_kernel(const int* __restrict__ rows, const int* __restrict__ cols,
                               const float* __restrict__ vals, int* __restrict__ fill,
                               int* __restrict__ cols_s, float* __restrict__ vals_s) {
    int e = blockIdx.x * 256 + threadIdx.x;
    int p = atomicAdd(&fill[rows[e]], 1);
    cols_s[p] = cols[e];
    vals_s[p] = vals[e];
}

// ---------------- CSR spmm: one 64-lane wave per output row, no atomics ----------------
// y[b, r, 0:32] = sum_e vals[e] * x[b, cols[e], 0:32]; lane = (batch-pair, channel)
__global__ __launch_bounds__(256) void spmm_csr_kernel(
    const int* __restrict__ rowptr, const int* __restrict__ cols,
    const float* __restrict__ vals, const float* __restrict__ x,
    float* __restrict__ y, int K4, int R4) {
    int r = blockIdx.x * 4 + (threadIdx.x >> 6);
    int lane = threadIdx.x & 63;
    int b = lane >> 5;      // batches b and b+2
    int c = lane & 31;
    size_t bs = (size_t)K4 * 32;
    const float* x0 = x + (size_t)b * bs + c;
    const float* x1 = x + (size_t)(b + 2) * bs + c;
    int e0 = rowptr[r], e1 = rowptr[r + 1];
    float a0 = 0.f, a1 = 0.f;
    for (int e = e0; e < e1; ++e) {
        int co = cols[e];
        float va = vals[e];
        size_t o = (size_t)co * 32;
        a0 += va * x0[o];
        a1 += va * x1[o];
    }
    size_t rs = (size_t)R4 * 32;
    size_t ro = (size_t)r * 32 + c;
    y[(size_t)b * rs + ro] = a0;
    y[(size_t)(b + 2) * rs + ro] = a1;
}

// per-channel sums/sumsq over rows of X = [elu(A) | B-half]; S[0:256]=sum, S[256:512]=sumsq
__global__ void stats_kernel(const float* __restrict__ A, const float* __restrict__ Bs,
                             float* __restrict__ S, int R, int rpb, int rowsPerBatch,
                             int modeB, int eluB) {
    int t = threadIdx.x;
    int r0 = blockIdx.x * rpb;
    int r1 = min(r0 + rpb, R);
    float s1 = 0.f, s2 = 0.f;
    if (t < 128) {
        for (int r = r0; r < r1; ++r) {
            float v = eluf(A[(size_t)r * 128 + t]);
            s1 += v; s2 += v * v;
        }
    } else {
        int c = t - 128;
        if (modeB == 0) {
            for (int r = r0; r < r1; ++r) {
                float v = Bs[(size_t)r * 128 + c];
                if (eluB) v = eluf(v);
                s1 += v; s2 += v * v;
            }
        } else {
            for (int r = r0; r < r1; ++r) {
                float v = Bs[(r / rowsPerBatch) * 128 + c];
                s1 += v; s2 += v * v;
            }
        }
    }
    atomicAdd(&S[t], s1);
    atomicAdd(&S[256 + t], s2);
}

// Fold BN into weights: Wp[k,o] = s_k*W[k,o]; bp[o] = b[o] + sum_k (beta_k - mean_k*s_k)*W[k,o]
__global__ void fold_kernel(const float* __restrict__ S, const float* __restrict__ gamma,
                            const float* __restrict__ beta, const float* __restrict__ W,
                            const float* __restrict__ bvec, float* __restrict__ Wp,
                            float* __restrict__ bp, float invR) {
    __shared__ float red[256];
    int o = blockIdx.x, k = threadIdx.x;
    float mean = S[k] * invR;
    float var = S[256 + k] * invR - mean * mean;
    float s = gamma[k] / sqrtf(var + EPS);
    float w = W[(size_t)k * 128 + o];
    Wp[(size_t)k * 128 + o] = s * w;
    red[k] = (beta[k] - mean * s) * w;
    __syncthreads();
    for (int st = 128; st > 0; st >>= 1) {
        if (k < st) red[k] += red[k + st];
        __syncthreads();
    }
    if (k == 0) bp[o] = bvec[o] + red[0];
}

// GEMM: out[r, 0:128] = X[r, 0:256] @ Wp + bp (+ resid). X half A = elu(A[r]), half B per mode.
__global__ __launch_bounds__(128) void gemm256(
    const float* __restrict__ A, const float* __restrict__ Bs,
    const float* __restrict__ Wp, const float* __restrict__ bp,
    const float* __restrict__ resid, float* __restrict__ out,
    int rowsPerBatch, int modeB, int eluB) {
    __shared__ float Xs[32][68];   // [kk][row] transposed, padded
    __shared__ float Ws[32][132];  // [kk][col] padded
    const int t = threadIdx.x;
    const int tcol = t & 15, trow = t >> 4;
    const int rowBase = blockIdx.x * 64;
    float acc[8][8];
#pragma unroll
    for (int i = 0; i < 8; ++i)
#pragma unroll
        for (int j = 0; j < 8; ++j) acc[i][j] = 0.f;

    for (int kb = 0; kb < 8; ++kb) {
        __syncthreads();
#pragma unroll
        for (int j = 0; j < 8; ++j) {
            int idx = t + 128 * j;
            int kr = idx >> 5, cq = (idx & 31) << 2;
            float4 w = *(const float4*)&Wp[(size_t)(kb * 32 + kr) * 128 + cq];
            *(float4*)&Ws[kr][cq] = w;
        }
#pragma unroll
        for (int j = 0; j < 4; ++j) {
            int idx = t + 128 * j;
            int row = idx >> 3, q = idx & 7;
            int gr = rowBase + row;
            int lc = q * 4;
            float4 v;
            if (kb < 4) {
                v = elu4(*(const float4*)&A[(size_t)gr * 128 + kb * 32 + lc]);
            } else if (modeB == 0) {
                v = *(const float4*)&Bs[(size_t)gr * 128 + (kb - 4) * 32 + lc];
                if (eluB) v = elu4(v);
            } else {
                int b = gr / rowsPerBatch;
                v = *(const float4*)&Bs[b * 128 + (kb - 4) * 32 + lc];
            }
            Xs[lc + 0][row] = v.x;
            Xs[lc + 1][row] = v.y;
            Xs[lc + 2][row] = v.z;
            Xs[lc + 3][row] = v.w;
        }
        __syncthreads();
#pragma unroll
        for (int kk = 0; kk < 32; ++kk) {
            float4 x0 = *(const float4*)&Xs[kk][trow * 8];
            float4 x1 = *(const float4*)&Xs[kk][trow * 8 + 4];
            float4 w0 = *(const float4*)&Ws[kk][tcol * 8];
            float4 w1 = *(const float4*)&Ws[kk][tcol * 8 + 4];
            float xv[8] = {x0.x, x0.y, x0.z, x0.w, x1.x, x1.y, x1.z, x1.w};
            float wv[8] = {w0.x, w0.y, w0.z, w0.w, w1.x, w1.y, w1.z, w1.w};
#pragma unroll
            for (int i = 0; i < 8; ++i)
#pragma unroll
                for (int j = 0; j < 8; ++j) acc[i][j] += xv[i] * wv[j];
        }
    }
    const int c0 = tcol * 8;
    float4 b0 = *(const float4*)&bp[c0];
    float4 b1 = *(const float4*)&bp[c0 + 4];
#pragma unroll
    for (int i = 0; i < 8; ++i) {
        size_t ro = (size_t)(rowBase + trow * 8 + i) * 128 + c0;
        float4 o0 = make_float4(acc[i][0] + b0.x, acc[i][1] + b0.y, acc[i][2] + b0.z, acc[i][3] + b0.w);
        float4 o1 = make_float4(acc[i][4] + b1.x, acc[i][5] + b1.y, acc[i][6] + b1.z, acc[i][7] + b1.w);
        if (resid) {
            float4 r0 = *(const float4*)&resid[ro];
            float4 r1 = *(const float4*)&resid[ro + 4];
            o0.x += r0.x; o0.y += r0.y; o0.z += r0.z; o0.w += r0.w;
            o1.x += r1.x; o1.y += r1.y; o1.z += r1.z; o1.w += r1.w;
        }
        *(float4*)&out[ro] = o0;
        *(float4*)&out[ro + 4] = o1;
    }
}

// masked mean of elu(X) over rows per batch: partial sums via atomics
__global__ void avgpool_kernel(const float* __restrict__ X, const float* __restrict__ mask,
                               float* __restrict__ avgacc, float* __restrict__ masksum,
                               int N, int rpb) {
    int b = blockIdx.y, t = threadIdx.x;
    int n0 = blockIdx.x * rpb;
    int n1 = min(n0 + rpb, N);
    float acc = 0.f, mac = 0.f;
    for (int n = n0; n < n1; ++n) {
        float m = mask[(size_t)b * N + n];
        float v = eluf(X[((size_t)b * N + n) * 128 + t]);
        acc += m * v;
        mac += m;
    }
    atomicAdd(&avgacc[b * 128 + t], acc);
    if (t == 0) atomicAdd(&masksum[b], mac);
}

// avg[b,c] = acc/masksum; also fill broadcast-half BN sums: S[128+c], S[384+c]
__global__ void finalize_avg(const float* __restrict__ avgacc, const float* __restrict__ masksum,
                             float* __restrict__ avg, float* __restrict__ S, float fN) {
    int c = threadIdx.x;
    float s1 = 0.f, s2 = 0.f;
    for (int b = 0; b < 4; ++b) {
        float a = avgacc[b * 128 + c] / masksum[b];
        avg[b * 128 + c] = a;
        s1 += a; s2 += a * a;
    }
    S[128 + c] = s1 * fN;
    S[256 + 128 + c] = s2 * fN;
}

// final conv fold: W2p[c] = s_c*W2[c]; W2p[128] = b2 + sum_c (be2_c - mean_c*s_c)*W2[c]
__global__ void fold_final(const float* __restrict__ S, const float* __restrict__ g2,
                           const float* __restrict__ be2, const float* __restrict__ W2,
                           const float* __restrict__ b2, float* __restrict__ W2p, float invR) {
    __shared__ float red[128];
    int c = threadIdx.x;
    float mean = S[c] * invR;
    float var = S[256 + c] * invR - mean * mean;
    float s = g2[c] / sqrtf(var + EPS);
    float w = W2[c];
    W2p[c] = s * w;
    red[c] = (be2[c] - mean * s) * w;
    __syncthreads();
    for (int st = 64; st > 0; st >>= 1) {
        if (c < st) red[c] += red[c + st];
        __syncthreads();
    }
    if (c == 0) W2p[128] = b2[0] + red[0];
}

// out[row] = elu(f[row,:]) . W2p[0:128] + W2p[128]; one wave per row
__global__ void final_out_kernel(const float* __restrict__ f, const float* __restrict__ W2p,
                                 float* __restrict__ out) {
    int t = threadIdx.x;
    int w = t >> 6, lane = t & 63;
    int row = blockIdx.x * 4 + w;
    float a = eluf(f[(size_t)row * 128 + lane]) * W2p[lane] +
              eluf(f[(size_t)row * 128 + 64 + lane]) * W2p[64 + lane];
    for (int off = 32; off > 0; off >>= 1) a += __shfl_down(a, off);
    if (lane == 0) out[row] = a + W2p[128];
}

extern "C" void kernel_launch(void* const* d_in, const int* in_sizes, int n_in,
                              void* d_out, int out_size, void* d_ws, size_t ws_size,
                              hipStream_t stream) {
    const float* inputs = (const float*)d_in[0];
    const float* mask = (const float*)d_in[1];
    const int* Di_rows = (const int*)d_in[2];
    const int* Di_cols = (const int*)d_in[3];
    const float* Di_vals = (const float*)d_in[4];
    const int* DiA_rows = (const int*)d_in[5];
    const int* DiA_cols = (const int*)d_in[6];
    const float* DiA_vals = (const float*)d_in[7];
    const float* W1 = (const float*)d_in[8];
    const float* b1 = (const float*)d_in[9];
    const float* rn_gamma = (const float*)d_in[10];
    const float* rn_beta = (const float*)d_in[11];
    const float* rn_W = (const float*)d_in[12];
    const float* rn_b = (const float*)d_in[13];
    const float* g2 = (const float*)d_in[14];
    const float* be2 = (const float*)d_in[15];
    const float* W2 = (const float*)d_in[16];
    const float* b2 = (const float*)d_in[17];
    float* out = (float*)d_out;

    const int B = 4;
    const int BN = in_sizes[1];      // B*N = 48000
    const int N = BN / B;            // 12000
    const int BF = out_size;         // B*Fn = 96000
    const int Fn = BF / B;           // 24000
    const int nnz = in_sizes[2];     // 1,152,000
    const int RA = 4 * N;            // DiA output rows = 48000
    const int RD = 4 * Fn;           // Di output rows = 96000

    // workspace layout (floats); ~142 MB total (round-1 used ~148MB OK)
    float* ws = (float*)d_ws;
    size_t off = 0;
    float* vA = ws + off;  off += (size_t)BN * 128;   // vertex features (in-place updated)
    float* fA = ws + off;  off += (size_t)BF * 128;   // face features (in-place updated)
    float* msg = ws + off; off += (size_t)BF * 128;   // spmm output; doubles as xT in avg blocks
    // CSR for DiA (rows in 4N space) and Di (rows in 4Fn space)
    int* ptrA   = (int*)(ws + off);   off += (size_t)RA + 4;
    int* colsA  = (int*)(ws + off);   off += (size_t)nnz;
    float* valsA = ws + off;          off += (size_t)nnz;
    int* ptrD   = (int*)(ws + off);   off += (size_t)RD + 4;
    int* colsD  = (int*)(ws + off);   off += (size_t)nnz;
    float* valsD = ws + off;          off += (size_t)nnz;
    int* tmpfill = (int*)(ws + off);  off += (size_t)RD;  // counts, then fill cursor
    float* S = ws + off;      off += 512;             // BN sums/sumsq
    float* avgacc = ws + off; off += 512;
    float* masksum = ws + off; off += 4;
    float* avg = ws + off;    off += 512;
    float* Wp = ws + off;  off += 256 * 128;          // folded weights
    float* bp = ws + off;  off += 128;                // folded bias
    float* W2p = ws + off; off += 132;                // final folded weights + bias

    const int eBlocks = nnz / 256;

    // ---- build CSR for DiA ----
    hipMemsetAsync(tmpfill, 0, (size_t)RA * 4, stream);
    hist_kernel<<<eBlocks, 256, 0, stream>>>(DiA_rows, tmpfill);
    scan_kernel<<<1, 1024, 0, stream>>>(tmpfill, ptrA, RA, nnz);
    hipMemcpyAsync(tmpfill, ptrA, (size_t)RA * 4, hipMemcpyDeviceToDevice, stream);
    scatter_kernel<<<eBlocks, 256, 0, stream>>>(DiA_rows, DiA_cols, DiA_vals, tmpfill,
                                                colsA, valsA);
    // ---- build CSR for Di ----
    hipMemsetAsync(tmpfill, 0, (size_t)RD * 4, stream);
    hist_kernel<<<eBlocks, 256, 0, stream>>>(Di_rows, tmpfill);
    scan_kernel<<<1, 1024, 0, stream>>>(tmpfill, ptrD, RD, nnz);
    hipMemcpyAsync(tmpfill, ptrD, (size_t)RD * 4, hipMemcpyDeviceToDevice, stream);
    scatter_kernel<<<eBlocks, 256, 0, stream>>>(Di_rows, Di_cols, Di_vals, tmpfill,
                                                colsD, valsD);

    hipMemsetAsync(fA, 0, (size_t)BF * 128 * 4, stream);
    conv1_kernel<<<BN * 128 / 256, 256, 0, stream>>>(inputs, W1, b1, vA);

    for (int i = 0; i < 16; ++i) {
        if ((i & 1) == 0) {
            // ---- dir block ----
            const float* g0 = rn_gamma + (size_t)(i * 2 + 0) * 256;
            const float* be0 = rn_beta + (size_t)(i * 2 + 0) * 256;
            const float* Wl0 = rn_W + (size_t)(i * 2 + 0) * 256 * 128;
            const float* bl0 = rn_b + (size_t)(i * 2 + 0) * 128;
            const float* g1 = rn_gamma + (size_t)(i * 2 + 1) * 256;
            const float* be1 = rn_beta + (size_t)(i * 2 + 1) * 256;
            const float* Wl1 = rn_W + (size_t)(i * 2 + 1) * 256 * 128;
            const float* bl1 = rn_b + (size_t)(i * 2 + 1) * 128;

            // msg_v = DiA @ f
            spmm_csr_kernel<<<RA / 4, 256, 0, stream>>>(ptrA, colsA, valsA, fA, msg, RD, RA);
            hipMemsetAsync(S, 0, 512 * 4, stream);
            stats_kernel<<<BN / 64, 256, 0, stream>>>(vA, msg, S, BN, 64, N, 0, 1);
            fold_kernel<<<128, 256, 0, stream>>>(S, g0, be0, Wl0, bl0, Wp, bp, 1.f / BN);
            gemm256<<<BN / 64, 128, 0, stream>>>(vA, msg, Wp, bp, vA, vA, N, 0, 1);

            // msg_f = Di @ v_out
            spmm_csr_kernel<<<RD / 4, 256, 0, stream>>>(ptrD, colsD, valsD, vA, msg, RA, RD);
            hipMemsetAsync(S, 0, 512 * 4, stream);
            stats_kernel<<<BF / 64, 256, 0, stream>>>(fA, msg, S, BF, 64, Fn, 0, 1);
            fold_kernel<<<128, 256, 0, stream>>>(S, g1, be1, Wl1, bl1, Wp, bp, 1.f / BF);
            gemm256<<<BF / 64, 128, 0, stream>>>(fA, msg, Wp, bp, nullptr, fA, Fn, 0, 1);
        } else {
            // ---- avg block ---- (msg is free here; used as the intermediate x)
            for (int j = 0; j < 2; ++j) {
                const float* g = rn_gamma + (size_t)(i * 2 + j) * 256;
                const float* be = rn_beta + (size_t)(i * 2 + j) * 256;
                const float* Wl = rn_W + (size_t)(i * 2 + j) * 256 * 128;
                const float* bl = rn_b + (size_t)(i * 2 + j) * 128;
                const float* src = (j == 0) ? vA : msg;
                float* dst = (j == 0) ? msg : vA;
                const float* resid = (j == 0) ? nullptr : vA;

                hipMemsetAsync(avgacc, 0, (512 + 4) * 4, stream);  // avgacc + masksum
                avgpool_kernel<<<dim3(N / 50, B), 128, 0, stream>>>(src, mask, avgacc, masksum,
                                                                    N, 50);
                hipMemsetAsync(S, 0, 512 * 4, stream);
                finalize_avg<<<1, 128, 0, stream>>>(avgacc, masksum, avg, S, (float)N);
                stats_kernel<<<BN / 64, 128, 0, stream>>>(src, nullptr, S, BN, 64, N, 0, 0);
                fold_kernel<<<128, 256, 0, stream>>>(S, g, be, Wl, bl, Wp, bp, 1.f / BN);
                gemm256<<<BN / 64, 128, 0, stream>>>(src, avg, Wp, bp, resid, dst, N, 1, 0);
            }
        }
    }

    // final conv2 on elu(f)
    hipMemsetAsync(S, 0, 512 * 4, stream);
    stats_kernel<<<BF / 64, 128, 0, stream>>>(fA, nullptr, S, BF, 64, Fn, 0, 0);
    fold_final<<<1, 128, 0, stream>>>(S, g2, be2, W2, b2, W2p, 1.f / BF);
    final_out_kernel<<<BF / 4, 256, 0, stream>>>(fA, W2p, out);
}

// Round 3
// 6634.380 us; speedup vs baseline: 2.0024x; 1.2401x over previous
//
#include <hip/hip_runtime.h>
#include <math.h>

// DirModelToFace on MI355X — round 3:
//  * GEMM -> MFMA bf16 hi/lo split (AhBh+AhBl+AlBh, fp32 acc): near-fp32 accuracy,
//    ~3x372 GFLOP on matrix cores instead of 124 GFLOP on the 157TF vector ALU.
//  * fold_kernel pre-splits BN-folded W into bf16 hi/lo, [col][k] layout for B-frags.
//  * single-block scan (168us x2) -> hierarchical 3-kernel scan (~15us).
// Round-2 profile: scan_kernel 168us top real dispatch; GEMM bucket ~2.1ms (fp32 VALU).

#define EPS 1e-5f

typedef float floatx4 __attribute__((ext_vector_type(4)));
typedef short shortx8 __attribute__((ext_vector_type(8)));

__device__ __forceinline__ float eluf(float x) { return x > 0.f ? x : expm1f(x); }
__device__ __forceinline__ float4 elu4(float4 v) {
    v.x = eluf(v.x); v.y = eluf(v.y); v.z = eluf(v.z); v.w = eluf(v.w); return v;
}
__device__ __forceinline__ short f2bf(float x) {  // round-to-nearest-even bf16
    unsigned u = __builtin_bit_cast(unsigned, x);
    u = u + 0x7FFFu + ((u >> 16) & 1u);
    return (short)(u >> 16);
}
__device__ __forceinline__ float bf2f(short h) {
    unsigned u = ((unsigned)(unsigned short)h) << 16;
    return __builtin_bit_cast(float, u);
}

// v = inputs @ W1 + b1   (inputs [BN,3], W1 [3,128])
__global__ void conv1_kernel(const float* __restrict__ in, const float* __restrict__ W1,
                             const float* __restrict__ b1, float* __restrict__ v) {
    int idx = blockIdx.x * 256 + threadIdx.x;
    int r = idx >> 7, c = idx & 127;
    float x0 = in[r * 3 + 0], x1 = in[r * 3 + 1], x2 = in[r * 3 + 2];
    v[(size_t)r * 128 + c] = b1[c] + x0 * W1[c] + x1 * W1[128 + c] + x2 * W1[256 + c];
}

// ---------------- CSR build (per launch; amortized over 8 spmm uses) ----------------

__global__ void hist_kernel(const int* __restrict__ rows, int* __restrict__ counts) {
    int e = blockIdx.x * 256 + threadIdx.x;
    atomicAdd(&counts[rows[e]], 1);
}

// hierarchical scan: per-1024-chunk sums
__global__ void partial_kernel(const int* __restrict__ counts, int* __restrict__ partials,
                               int R) {
    int t = threadIdx.x;
    int base = blockIdx.x * 1024 + t * 4;
    int s = 0;
#pragma unroll
    for (int j = 0; j < 4; ++j) { int i = base + j; if (i < R) s += counts[i]; }
    __shared__ int sh[256];
    sh[t] = s; __syncthreads();
    for (int st = 128; st > 0; st >>= 1) {
        if (t < st) sh[t] += sh[t + st];
        __syncthreads();
    }
    if (t == 0) partials[blockIdx.x] = sh[0];
}

// exclusive scan of <=256 partials in one block; also writes rowptr[R]=total
__global__ void scanp_kernel(int* __restrict__ partials, int* __restrict__ rowptr,
                             int P, int R, int total) {
    __shared__ int sh[256];
    int t = threadIdx.x;
    int v = (t < P) ? partials[t] : 0;
    sh[t] = v; __syncthreads();
    for (int st = 1; st < 256; st <<= 1) {
        int tmp = (t >= st) ? sh[t - st] : 0;
        __syncthreads();
        sh[t] += tmp;
        __syncthreads();
    }
    if (t < P) partials[t] = sh[t] - v;
    if (t == 0) rowptr[R] = total;
}

// per-chunk exclusive scan + partial offset -> rowptr
__global__ void apply_kernel(const int* __restrict__ counts, const int* __restrict__ partials,
                             int* __restrict__ rowptr, int R) {
    int t = threadIdx.x;
    int base = blockIdx.x * 1024 + t * 4;
    int c[4]; int s = 0;
#pragma unroll
    for (int j = 0; j < 4; ++j) { int i = base + j; c[j] = (i < R) ? counts[i] : 0; s += c[j]; }
    __shared__ int sh[256];
    sh[t] = s; __syncthreads();
    for (int st = 1; st < 256; st <<= 1) {
        int tmp = (t >= st) ? sh[t - st] : 0;
        __syncthreads();
        sh[t] += tmp;
        __syncthreads();
    }
    int off = partials[blockIdx.x] + sh[t] - s;
#pragma unroll
    for (int j = 0; j < 4; ++j) { int i = base + j; if (i < R) rowptr[i] = off; off += c[j]; }
}

__global__ void scatter_kernel(const int* __restrict__ rows, const int* __restrict__ cols,
                               const float* __restrict__ vals, int* __restrict__ fill,
                               int* __restrict__ cols_s, float* __restrict__ vals_s) {
    int e = blockIdx.x * 256 + threadIdx.x;
    int p = atomicAdd(&fill[rows[e]], 1);
    cols_s[p] = cols[e];
    vals_s[p] = vals[e];
}

// ---------------- CSR spmm: one 64-lane wave per output row, no atomics ----------------
__global__ __launch_bounds__(256) void spmm_csr_kernel(
    const int* __restrict__ rowptr, const int* __restrict__ cols,
    const float* __restrict__ vals, const float* __restrict__ x,
    float* __restrict__ y, int K4, int R4) {
    int r = blockIdx.x * 4 + (threadIdx.x >> 6);
    int lane = threadIdx.x & 63;
    int b = lane >> 5;
    int c = lane & 31;
    size_t bs = (size_t)K4 * 32;
    const float* x0 = x + (size_t)b * bs + c;
    const float* x1 = x + (size_t)(b + 2) * bs + c;
    int e0 = rowptr[r], e1 = rowptr[r + 1];
    float a0 = 0.f, a1 = 0.f;
    for (int e = e0; e < e1; ++e) {
        int co = cols[e];
        float va = vals[e];
        size_t o = (size_t)co * 32;
        a0 += va * x0[o];
        a1 += va * x1[o];
    }
    size_t rs = (size_t)R4 * 32;
    size_t ro = (size_t)r * 32 + c;
    y[(size_t)b * rs + ro] = a0;
    y[(size_t)(b + 2) * rs + ro] = a1;
}

// per-channel sums/sumsq over rows of X = [elu(A) | B-half]; S[0:256]=sum, S[256:512]=sumsq
__global__ void stats_kernel(const float* __restrict__ A, const float* __restrict__ Bs,
                             float* __restrict__ S, int R, int rpb, int rowsPerBatch,
                             int modeB, int eluB) {
    int t = threadIdx.x;
    int r0 = blockIdx.x * rpb;
    int r1 = min(r0 + rpb, R);
    float s1 = 0.f, s2 = 0.f;
    if (t < 128) {
        for (int r = r0; r < r1; ++r) {
            float v = eluf(A[(size_t)r * 128 + t]);
            s1 += v; s2 += v * v;
        }
    } else {
        int c = t - 128;
        if (modeB == 0) {
            for (int r = r0; r < r1; ++r) {
                float v = Bs[(size_t)r * 128 + c];
                if (eluB) v = eluf(v);
                s1 += v; s2 += v * v;
            }
        } else {
            for (int r = r0; r < r1; ++r) {
                float v = Bs[(r / rowsPerBatch) * 128 + c];
                s1 += v; s2 += v * v;
            }
        }
    }
    atomicAdd(&S[t], s1);
    atomicAdd(&S[256 + t], s2);
}

// Fold BN into weights; emit bf16 hi/lo split in [col][k] layout for MFMA B-frags.
__global__ void fold_kernel(const float* __restrict__ S, const float* __restrict__ gamma,
                            const float* __restrict__ beta, const float* __restrict__ W,
                            const float* __restrict__ bvec, short* __restrict__ Wh,
                            short* __restrict__ Wl, float* __restrict__ bp, float invR) {
    __shared__ float red[256];
    int o = blockIdx.x, k = threadIdx.x;
    float mean = S[k] * invR;
    float var = S[256 + k] * invR - mean * mean;
    float s = gamma[k] / sqrtf(var + EPS);
    float w = W[(size_t)k * 128 + o];
    float wp = s * w;
    short h = f2bf(wp);
    Wh[(size_t)o * 256 + k] = h;
    Wl[(size_t)o * 256 + k] = f2bf(wp - bf2f(h));
    red[k] = (beta[k] - mean * s) * w;
    __syncthreads();
    for (int st = 128; st > 0; st >>= 1) {
        if (k < st) red[k] += red[k + st];
        __syncthreads();
    }
    if (k == 0) bp[o] = bvec[o] + red[0];
}

// MFMA GEMM: out[r,0:128] = X[r,0:256] @ W + bp (+resid), X = [elu(A) | B-half].
// bf16 hi/lo split (3 mfma products) -> near-fp32 accuracy. LDS-free: wave owns
// 32 rows x 128 cols; A fp32->split in-reg; B-frags from hot 64KB Wh/Wl (L1/L2).
__global__ __launch_bounds__(256) void gemm_mfma(
    const float* __restrict__ A, const float* __restrict__ Bs,
    const short* __restrict__ Wh, const short* __restrict__ Wl,
    const float* __restrict__ bp, const float* __restrict__ resid,
    float* __restrict__ out, int rowsPerBatch, int modeB, int eluB) {
    const int lane = threadIdx.x & 63;
    const int wave = threadIdx.x >> 6;
    const int rowBase = blockIdx.x * 128 + wave * 32;
    const int m = lane & 15;
    const int kq = lane >> 4;
    floatx4 acc[2][8];
#pragma unroll
    for (int i = 0; i < 2; ++i)
#pragma unroll
        for (int j = 0; j < 8; ++j) acc[i][j] = {0.f, 0.f, 0.f, 0.f};

    for (int kb = 0; kb < 8; ++kb) {
        const int k0 = kb * 32 + kq * 8;
        shortx8 ah[2], al[2];
#pragma unroll
        for (int rg = 0; rg < 2; ++rg) {
            int row = rowBase + rg * 16 + m;
            float4 p, q;
            if (kb < 4) {
                p = elu4(*(const float4*)&A[(size_t)row * 128 + k0]);
                q = elu4(*(const float4*)&A[(size_t)row * 128 + k0 + 4]);
            } else {
                int kk = k0 - 128;
                if (modeB == 0) {
                    p = *(const float4*)&Bs[(size_t)row * 128 + kk];
                    q = *(const float4*)&Bs[(size_t)row * 128 + kk + 4];
                    if (eluB) { p = elu4(p); q = elu4(q); }
                } else {
                    int b = row / rowsPerBatch;
                    p = *(const float4*)&Bs[b * 128 + kk];
                    q = *(const float4*)&Bs[b * 128 + kk + 4];
                }
            }
            float x[8] = {p.x, p.y, p.z, p.w, q.x, q.y, q.z, q.w};
#pragma unroll
            for (int j = 0; j < 8; ++j) {
                short h = f2bf(x[j]);
                ah[rg][j] = h;
                al[rg][j] = f2bf(x[j] - bf2f(h));
            }
        }
#pragma unroll
        for (int ct = 0; ct < 8; ++ct) {
            shortx8 bh = *(const shortx8*)&Wh[(size_t)(ct * 16 + m) * 256 + k0];
            shortx8 bl = *(const shortx8*)&Wl[(size_t)(ct * 16 + m) * 256 + k0];
#pragma unroll
            for (int rg = 0; rg < 2; ++rg) {
                acc[rg][ct] = __builtin_amdgcn_mfma_f32_16x16x32_bf16(ah[rg], bh, acc[rg][ct], 0, 0, 0);
                acc[rg][ct] = __builtin_amdgcn_mfma_f32_16x16x32_bf16(ah[rg], bl, acc[rg][ct], 0, 0, 0);
                acc[rg][ct] = __builtin_amdgcn_mfma_f32_16x16x32_bf16(al[rg], bh, acc[rg][ct], 0, 0, 0);
            }
        }
    }
    // epilogue: C/D layout col=lane&15, row=(lane>>4)*4+reg  [verified m89/m91]
#pragma unroll
    for (int ct = 0; ct < 8; ++ct) {
        int col = ct * 16 + m;
        float bb = bp[col];
#pragma unroll
        for (int rg = 0; rg < 2; ++rg) {
#pragma unroll
            for (int r = 0; r < 4; ++r) {
                int row = rowBase + rg * 16 + kq * 4 + r;
                size_t o = (size_t)row * 128 + col;
                float v = acc[rg][ct][r] + bb;
                if (resid) v += resid[o];
                out[o] = v;
            }
        }
    }
}

// masked mean of elu(X) over rows per batch: partial sums via atomics
__global__ void avgpool_kernel(const float* __restrict__ X, const float* __restrict__ mask,
                               float* __restrict__ avgacc, float* __restrict__ masksum,
                               int N, int rpb) {
    int b = blockIdx.y, t = threadIdx.x;
    int n0 = blockIdx.x * rpb;
    int n1 = min(n0 + rpb, N);
    float acc = 0.f, mac = 0.f;
    for (int n = n0; n < n1; ++n) {
        float m = mask[(size_t)b * N + n];
        float v = eluf(X[((size_t)b * N + n) * 128 + t]);
        acc += m * v;
        mac += m;
    }
    atomicAdd(&avgacc[b * 128 + t], acc);
    if (t == 0) atomicAdd(&masksum[b], mac);
}

__global__ void finalize_avg(const float* __restrict__ avgacc, const float* __restrict__ masksum,
                             float* __restrict__ avg, float* __restrict__ S, float fN) {
    int c = threadIdx.x;
    float s1 = 0.f, s2 = 0.f;
    for (int b = 0; b < 4; ++b) {
        float a = avgacc[b * 128 + c] / masksum[b];
        avg[b * 128 + c] = a;
        s1 += a; s2 += a * a;
    }
    S[128 + c] = s1 * fN;
    S[256 + 128 + c] = s2 * fN;
}

__global__ void fold_final(const float* __restrict__ S, const float* __restrict__ g2,
                           const float* __restrict__ be2, const float* __restrict__ W2,
                           const float* __restrict__ b2, float* __restrict__ W2p, float invR) {
    __shared__ float red[128];
    int c = threadIdx.x;
    float mean = S[c] * invR;
    float var = S[256 + c] * invR - mean * mean;
    float s = g2[c] / sqrtf(var + EPS);
    float w = W2[c];
    W2p[c] = s * w;
    red[c] = (be2[c] - mean * s) * w;
    __syncthreads();
    for (int st = 64; st > 0; st >>= 1) {
        if (c < st) red[c] += red[c + st];
        __syncthreads();
    }
    if (c == 0) W2p[128] = b2[0] + red[0];
}

__global__ void final_out_kernel(const float* __restrict__ f, const float* __restrict__ W2p,
                                 float* __restrict__ out) {
    int t = threadIdx.x;
    int w = t >> 6, lane = t & 63;
    int row = blockIdx.x * 4 + w;
    float a = eluf(f[(size_t)row * 128 + lane]) * W2p[lane] +
              eluf(f[(size_t)row * 128 + 64 + lane]) * W2p[64 + lane];
    for (int off = 32; off > 0; off >>= 1) a += __shfl_down(a, off);
    if (lane == 0) out[row] = a + W2p[128];
}

extern "C" void kernel_launch(void* const* d_in, const int* in_sizes, int n_in,
                              void* d_out, int out_size, void* d_ws, size_t ws_size,
                              hipStream_t stream) {
    const float* inputs = (const float*)d_in[0];
    const float* mask = (const float*)d_in[1];
    const int* Di_rows = (const int*)d_in[2];
    const int* Di_cols = (const int*)d_in[3];
    const float* Di_vals = (const float*)d_in[4];
    const int* DiA_rows = (const int*)d_in[5];
    const int* DiA_cols = (const int*)d_in[6];
    const float* DiA_vals = (const float*)d_in[7];
    const float* W1 = (const float*)d_in[8];
    const float* b1 = (const float*)d_in[9];
    const float* rn_gamma = (const float*)d_in[10];
    const float* rn_beta = (const float*)d_in[11];
    const float* rn_W = (const float*)d_in[12];
    const float* rn_b = (const float*)d_in[13];
    const float* g2 = (const float*)d_in[14];
    const float* be2 = (const float*)d_in[15];
    const float* W2 = (const float*)d_in[16];
    const float* b2 = (const float*)d_in[17];
    float* out = (float*)d_out;

    const int B = 4;
    const int BN = in_sizes[1];      // 48000
    const int N = BN / B;            // 12000
    const int BF = out_size;         // 96000
    const int Fn = BF / B;           // 24000
    const int nnz = in_sizes[2];     // 1,152,000
    const int RA = 4 * N;            // 48000
    const int RD = 4 * Fn;           // 96000

    float* ws = (float*)d_ws;
    size_t off = 0;
    float* vA = ws + off;  off += (size_t)BN * 128;
    float* fA = ws + off;  off += (size_t)BF * 128;
    float* msg = ws + off; off += (size_t)BF * 128;
    int* ptrA   = (int*)(ws + off);   off += (size_t)RA + 4;
    int* colsA  = (int*)(ws + off);   off += (size_t)nnz;
    float* valsA = ws + off;          off += (size_t)nnz;
    int* ptrD   = (int*)(ws + off);   off += (size_t)RD + 4;
    int* colsD  = (int*)(ws + off);   off += (size_t)nnz;
    float* valsD = ws + off;          off += (size_t)nnz;
    int* tmpfill = (int*)(ws + off);  off += (size_t)RD;
    int* partials = (int*)(ws + off); off += 256;
    float* S = ws + off;      off += 512;
    float* avgacc = ws + off; off += 512;
    float* masksum = ws + off; off += 4;
    float* avg = ws + off;    off += 512;
    short* Wh = (short*)(ws + off); off += 128 * 256 / 2;  // bf16 [col][k]
    short* Wl = (short*)(ws + off); off += 128 * 256 / 2;
    float* bp = ws + off;  off += 128;
    float* W2p = ws + off; off += 132;

    const int eBlocks = nnz / 256;
    const int PA = (RA + 1023) / 1024;
    const int PD = (RD + 1023) / 1024;

    // ---- build CSR for DiA ----
    hipMemsetAsync(tmpfill, 0, (size_t)RA * 4, stream);
    hist_kernel<<<eBlocks, 256, 0, stream>>>(DiA_rows, tmpfill);
    partial_kernel<<<PA, 256, 0, stream>>>(tmpfill, partials, RA);
    scanp_kernel<<<1, 256, 0, stream>>>(partials, ptrA, PA, RA, nnz);
    apply_kernel<<<PA, 256, 0, stream>>>(tmpfill, partials, ptrA, RA);
    hipMemcpyAsync(tmpfill, ptrA, (size_t)RA * 4, hipMemcpyDeviceToDevice, stream);
    scatter_kernel<<<eBlocks, 256, 0, stream>>>(DiA_rows, DiA_cols, DiA_vals, tmpfill,
                                                colsA, valsA);
    // ---- build CSR for Di ----
    hipMemsetAsync(tmpfill, 0, (size_t)RD * 4, stream);
    hist_kernel<<<eBlocks, 256, 0, stream>>>(Di_rows, tmpfill);
    partial_kernel<<<PD, 256, 0, stream>>>(tmpfill, partials, RD);
    scanp_kernel<<<1, 256, 0, stream>>>(partials, ptrD, PD, RD, nnz);
    apply_kernel<<<PD, 256, 0, stream>>>(tmpfill, partials, ptrD, RD);
    hipMemcpyAsync(tmpfill, ptrD, (size_t)RD * 4, hipMemcpyDeviceToDevice, stream);
    scatter_kernel<<<eBlocks, 256, 0, stream>>>(Di_rows, Di_cols, Di_vals, tmpfill,
                                                colsD, valsD);

    hipMemsetAsync(fA, 0, (size_t)BF * 128 * 4, stream);
    conv1_kernel<<<BN * 128 / 256, 256, 0, stream>>>(inputs, W1, b1, vA);

    for (int i = 0; i < 16; ++i) {
        if ((i & 1) == 0) {
            const float* g0 = rn_gamma + (size_t)(i * 2 + 0) * 256;
            const float* be0 = rn_beta + (size_t)(i * 2 + 0) * 256;
            const float* Wl0 = rn_W + (size_t)(i * 2 + 0) * 256 * 128;
            const float* bl0 = rn_b + (size_t)(i * 2 + 0) * 128;
            const float* g1 = rn_gamma + (size_t)(i * 2 + 1) * 256;
            const float* be1 = rn_beta + (size_t)(i * 2 + 1) * 256;
            const float* Wl1 = rn_W + (size_t)(i * 2 + 1) * 256 * 128;
            const float* bl1 = rn_b + (size_t)(i * 2 + 1) * 128;

            // msg_v = DiA @ f
            spmm_csr_kernel<<<RA / 4, 256, 0, stream>>>(ptrA, colsA, valsA, fA, msg, RD, RA);
            hipMemsetAsync(S, 0, 512 * 4, stream);
            stats_kernel<<<BN / 64, 256, 0, stream>>>(vA, msg, S, BN, 64, N, 0, 1);
            fold_kernel<<<128, 256, 0, stream>>>(S, g0, be0, Wl0, bl0, Wh, Wl, bp, 1.f / BN);
            gemm_mfma<<<BN / 128, 256, 0, stream>>>(vA, msg, Wh, Wl, bp, vA, vA, N, 0, 1);

            // msg_f = Di @ v_out
            spmm_csr_kernel<<<RD / 4, 256, 0, stream>>>(ptrD, colsD, valsD, vA, msg, RA, RD);
            hipMemsetAsync(S, 0, 512 * 4, stream);
            stats_kernel<<<BF / 64, 256, 0, stream>>>(fA, msg, S, BF, 64, Fn, 0, 1);
            fold_kernel<<<128, 256, 0, stream>>>(S, g1, be1, Wl1, bl1, Wh, Wl, bp, 1.f / BF);
            gemm_mfma<<<BF / 128, 256, 0, stream>>>(fA, msg, Wh, Wl, bp, nullptr, fA, Fn, 0, 1);
        } else {
            for (int j = 0; j < 2; ++j) {
                const float* g = rn_gamma + (size_t)(i * 2 + j) * 256;
                const float* be = rn_beta + (size_t)(i * 2 + j) * 256;
                const float* Wlw = rn_W + (size_t)(i * 2 + j) * 256 * 128;
                const float* bl = rn_b + (size_t)(i * 2 + j) * 128;
                const float* src = (j == 0) ? vA : msg;
                float* dst = (j == 0) ? msg : vA;
                const float* resid = (j == 0) ? nullptr : vA;

                hipMemsetAsync(avgacc, 0, (512 + 4) * 4, stream);
                avgpool_kernel<<<dim3(N / 50, B), 128, 0, stream>>>(src, mask, avgacc, masksum,
                                                                    N, 50);
                hipMemsetAsync(S, 0, 512 * 4, stream);
                finalize_avg<<<1, 128, 0, stream>>>(avgacc, masksum, avg, S, (float)N);
                stats_kernel<<<BN / 64, 128, 0, stream>>>(src, nullptr, S, BN, 64, N, 0, 0);
                fold_kernel<<<128, 256, 0, stream>>>(S, g, be, Wlw, bl, Wh, Wl, bp, 1.f / BN);
                gemm_mfma<<<BN / 128, 256, 0, stream>>>(src, avg, Wh, Wl, bp, resid, dst, N, 1, 0);
            }
        }
    }

    hipMemsetAsync(S, 0, 512 * 4, stream);
    stats_kernel<<<BF / 64, 128, 0, stream>>>(fA, nullptr, S, BF, 64, Fn, 0, 0);
    fold_final<<<1, 128, 0, stream>>>(S, g2, be2, W2, b2, W2p, 1.f / BF);
    final_out_kernel<<<BF / 4, 256, 0, stream>>>(fA, W2p, out);
}